// Round 1
// 171.823 us; speedup vs baseline: 1.0041x; 1.0041x over previous
//
#include <hip/hip_runtime.h>
#include <math.h>

#define KNN    10
#define NPTS   8192
#define HID    64
#define NF     76
#define Q      16                // queries per wave
#define CAP    64                // pass-2 collection capacity per query
#define F32_INF __uint_as_float(0x7F800000u)

__device__ __forceinline__ float rl(float v, int lane) {
    return __int_as_float(__builtin_amdgcn_readlane(__float_as_int(v), lane));
}

// ---------------------------------------------------------------------------
// KNN — R18 structure, R20 change: register-pressure fix.
//   Evidence: VGPR_Count=52 but hot loops need ~95 live VGPRs
//   (qxs/qys/qzs=48 + vmin=16 + qss=16 + cand dbuf/addr ~15). With bare
//   __launch_bounds__(512) the compiler targeted 8 waves/EU (<=64 VGPR) and
//   re-materialized/spilled the query arrays per tile -> ~3x instruction
//   inflation (86us VALU-issue vs 27us model), FETCH_SIZE stays low because
//   re-loads hit L1/L2.
//   Fix: __launch_bounds__(512, 4) -> 128-VGPR budget, 2 blocks/CU resident
//   (16 waves/CU, still enough TLP for the 1-tile-ahead prefetch), and drop
//   the qss[16] array (recompute qs in the rare hit branch with the
//   bit-identical fmaf chain) to free 16 more regs.
// Selection chain itself untouched (validated 10 rounds): inline w, transposed
// scan, rank-11 chunk-minima threshold + 1e-3, exact R1-chain key rebuild,
// top-11 + filter.
// ---------------------------------------------------------------------------
__global__ __launch_bounds__(512, 4) void knn_kernel(const float* __restrict__ cloud,
                                                     unsigned short* __restrict__ knn_idx) {
    __shared__ unsigned long long coll[CAP][33];   // 16.9 KB
    __shared__ float pk[8][Q][17];                 // 8.7 KB
    __shared__ float tau_s[32];
    __shared__ int   cnt[32];

    const int t    = threadIdx.x;
    const int w    = t >> 6;                  // wave 0..7
    const int lane = t & 63;
    const int g    = w >> 2;                  // query group 0..1
    const int h    = w & 3;                   // candidate quarter 0..3
    const int bx   = blockIdx.x;              // 0..1023
    const int b    = bx >> 8;                 // batch
    const int n_base = (bx & 255) * 32 + g * Q;   // batch-local first query of group
    const int lq_base = g * Q;                // block-local query base
    const int cb0 = h * (NPTS / 4);           // candidate base for this wave

    const float* cb = cloud + (size_t)b * NPTS * 3;

    if (t < 32) cnt[t] = 0;                   // visible after barrier 1

    float qxs[Q], qys[Q], qzs[Q];
#pragma unroll
    for (int qq = 0; qq < Q; ++qq) {
        qxs[qq] = cb[(n_base + qq) * 3 + 0];
        qys[qq] = cb[(n_base + qq) * 3 + 1];
        qzs[qq] = cb[(n_base + qq) * 3 + 2];
    }

    // ---------------- pass 1: per-lane minima over this quarter ----------------
    float vmin[Q];
#pragma unroll
    for (int qq = 0; qq < Q; ++qq) vmin[qq] = F32_INF;

    float cx0 = cb[(cb0 + lane) * 3 + 0];
    float cy0 = cb[(cb0 + lane) * 3 + 1];
    float cz0 = cb[(cb0 + lane) * 3 + 2];
    for (int ti = 0; ti < NPTS / 4 / 64; ++ti) {  // 32 tiles
        float nx0 = cx0, ny0 = cy0, nz0 = cz0;
        if (ti < NPTS / 4 / 64 - 1) {
            const int c1 = cb0 + (ti + 1) * 64 + lane;
            nx0 = cb[c1 * 3 + 0]; ny0 = cb[c1 * 3 + 1]; nz0 = cb[c1 * 3 + 2];
        }
        const float aw  = fmaf(cz0, cz0, fmaf(cy0, cy0, cx0 * cx0));  // prep expr
        const float a2x = -2.0f * cx0;
        const float a2y = -2.0f * cy0;
        const float a2z = -2.0f * cz0;
#pragma unroll
        for (int qq = 0; qq < Q; ++qq) {
            const float v = fmaf(a2x, qxs[qq], fmaf(a2y, qys[qq], fmaf(a2z, qzs[qq], aw)));
            vmin[qq] = fminf(vmin[qq], v);    // self included (rank arg handles it)
        }
        cx0 = nx0; cy0 = ny0; cz0 = nz0;
    }

#pragma unroll
    for (int qq = 0; qq < Q; ++qq) {
        float v = vmin[qq];
        v = fminf(v, __shfl_xor(v, 32, 64));
        v = fminf(v, __shfl_xor(v, 16, 64));
        if (lane < 16) pk[w][qq][lane] = v;
    }
    __syncthreads();                          // barrier 1: pk + cnt visible

    // h==0 waves: 11th smallest of 64 chunk minima -> tau for group
    if (h == 0) {
        float md[KNN + 1];
#pragma unroll
        for (int s = 0; s <= KNN; ++s) md[s] = F32_INF;
        const int qsel = lane & 15;           // 4-way replicated
#pragma unroll
        for (int cc = 0; cc < 64; ++cc) {
            float d = pk[g * 4 + (cc >> 4)][qsel][cc & 15];
#pragma unroll
            for (int u = 0; u <= KNN; ++u) {
                const float lo = fminf(md[u], d);
                d = fmaxf(md[u], d);
                md[u] = lo;
            }
        }
        if (lane < 16) tau_s[lq_base + lane] = md[KNN] + 1e-3f;
    }
    __syncthreads();                          // barrier 2: tau visible

    float taum[Q];
    {
        const float tv = tau_s[lq_base + (lane & 15)];
#pragma unroll
        for (int qq = 0; qq < Q; ++qq) taum[qq] = rl(tv, qq);   // -> SGPRs
    }

    // ---------------- pass 2: collect hits incl. self (rare) ----------------
    float cx2 = cb[(cb0 + lane) * 3 + 0];
    float cy2 = cb[(cb0 + lane) * 3 + 1];
    float cz2 = cb[(cb0 + lane) * 3 + 2];
    int jcur = cb0 + lane;
    for (int ti = 0; ti < NPTS / 4 / 64; ++ti) {
        float nx2 = cx2, ny2 = cy2, nz2 = cz2;
        if (ti < NPTS / 4 / 64 - 1) {
            const int c1 = cb0 + (ti + 1) * 64 + lane;
            nx2 = cb[c1 * 3 + 0]; ny2 = cb[c1 * 3 + 1]; nz2 = cb[c1 * 3 + 2];
        }
        const float aw  = fmaf(cz2, cz2, fmaf(cy2, cy2, cx2 * cx2));
        const float a2x = -2.0f * cx2;
        const float a2y = -2.0f * cy2;
        const float a2z = -2.0f * cz2;
#pragma unroll
        for (int qq = 0; qq < Q; ++qq) {
            const float v = fmaf(a2x, qxs[qq], fmaf(a2y, qys[qq], fmaf(a2z, qzs[qq], aw)));
            if (__builtin_expect(v <= taum[qq], 0)) {
                // EXACT key: R1-chain d2 expression. qs recomputed here with
                // the bit-identical fmaf chain (was qss[qq] array; freed 16
                // VGPRs — branch is rare so recompute is ~free).
                const float qs = fmaf(qzs[qq], qzs[qq],
                                      fmaf(qys[qq], qys[qq], qxs[qq] * qxs[qq]));
                const float dot = fmaf(cz2, qzs[qq], fmaf(cy2, qys[qq], cx2 * qxs[qq]));
                const float d2 = fmaf(-2.0f, dot, qs + aw);
                const unsigned int fb = __float_as_uint(d2);
                const unsigned int m =
                    fb ^ ((unsigned int)((int)fb >> 31) | 0x80000000u);  // monotone
                const unsigned long long key =
                    ((unsigned long long)m << 13) | (unsigned long long)(unsigned)jcur;
                const int slot = atomicAdd(&cnt[lq_base + qq], 1);
                if (slot < CAP) coll[slot][lq_base + qq] = key;
            }
        }
        cx2 = nx2; cy2 = ny2; cz2 = nz2;
        jcur += 64;
    }
    __syncthreads();

    // ---------------- phase 3: top-11 bubble, filter self by index ----------
    if (t < 32) {
        const int m = cnt[t];
        int mc = m;
#pragma unroll
        for (int off = 1; off < 32; off <<= 1)        // 32 active lanes only
            mc = max(mc, __shfl_xor(mc, off, 64));
        mc = __builtin_amdgcn_readfirstlane(mc);

        const int n = (bx & 255) * 32 + t;    // this lane's batch-local query

        unsigned long long md[KNN + 1];
#pragma unroll
        for (int s = 0; s <= KNN; ++s) md[s] = ~0ULL;

        if (mc <= CAP) {
            for (int cc = 0; cc < mc; ++cc) {
                unsigned long long key = (cc < m) ? coll[cc][t] : ~0ULL;
#pragma unroll
                for (int u = 0; u <= KNN; ++u) {
                    const bool lt = key < md[u];
                    const unsigned long long lo = lt ? key : md[u];
                    key = lt ? md[u] : key;
                    md[u] = lo;
                }
            }
        } else {
            // exact serial fallback (never expected): full rescan, inline w
            const float qx = cb[n * 3 + 0];
            const float qy = cb[n * 3 + 1];
            const float qz = cb[n * 3 + 2];
            const float qs = fmaf(qz, qz, fmaf(qy, qy, qx * qx));
            for (int j = 0; j < NPTS; ++j) {
                const float px = cb[j * 3 + 0];
                const float py = cb[j * 3 + 1];
                const float pz = cb[j * 3 + 2];
                const float pw = fmaf(pz, pz, fmaf(py, py, px * px));
                const float dot = fmaf(pz, qz, fmaf(py, qy, px * qx));
                const float d2 = fmaf(-2.0f, dot, qs + pw);
                const unsigned int fb = __float_as_uint(d2);
                const unsigned int mm =
                    fb ^ ((unsigned int)((int)fb >> 31) | 0x80000000u);
                unsigned long long key =
                    ((unsigned long long)mm << 13) | (unsigned long long)j;
                key = (j == n) ? ~0ULL : key;
#pragma unroll
                for (int u = 0; u <= KNN; ++u) {
                    const bool lt = key < md[u];
                    const unsigned long long lo = lt ? key : md[u];
                    key = lt ? md[u] : key;
                    md[u] = lo;
                }
            }
        }

        unsigned short* outp = knn_idx + ((size_t)b * NPTS + n) * KNN;
        int outc = 0;
#pragma unroll
        for (int u = 0; u <= KNN; ++u) {
            const int idx = (int)(md[u] & 8191u);
            if (outc < KNN && idx != n) outp[outc++] = (unsigned short)idx;
        }
    }
}

// ---------------------------------------------------------------------------
// Features + MLP — R18 config with QUAD-PARALLEL feature build (R19 change):
// the build previously ran on 1 of 4 lanes (10 serial gathers + cov + eigen
// = the longest unhidden chain at 2 waves/SIMD). Now lanes own 3/3/2/2
// neighbors (gather depth 10->3, same total fr LDS writes, just spread);
// mean/cov via quad partial sums + shfl_xor(1,2) reduces (~18 added shfl ops
// vs ~304 ds_read_b128/thread — negligible DS add, unlike R13's butterfly).
// Eigen redundant on all 4 lanes (same wave time), lane 0 writes.
// Tree-summed mean/cov: R13 used this pattern, absmax bit-identical.
// MLP part unchanged (best-measured R12/R14 layout).
// ---------------------------------------------------------------------------
__global__ __launch_bounds__(256) void feat_mlp_kernel(const float* __restrict__ cloud,
                                                       const float* __restrict__ W1,
                                                       const float* __restrict__ b1,
                                                       const float* __restrict__ W2,
                                                       const float* __restrict__ b2,
                                                       const unsigned short* __restrict__ knn_idx,
                                                       float* __restrict__ out) {
    __shared__ float w1s[NF * 68];            // padded stride
    __shared__ float b1s[HID];
    __shared__ float w2s[HID * 3];
    __shared__ float b2s[3];
    __shared__ float fs[64][NF + 1];          // stride 77

    const int t = threadIdx.x;
    for (int idx = t; idx < NF * HID; idx += 256)
        w1s[(idx >> 6) * 68 + (idx & 63)] = W1[idx];
    if (t < HID) b1s[t] = b1[t];
    if (t < HID * 3) w2s[t] = W2[t];
    if (t < 3) b2s[t] = b2[t];

    const int pl   = t >> 2;                  // point slot 0..63
    const int s    = t & 3;                   // quad sub-lane
    const int subh = t & 1;                   // hidden half
    const int subf = (t >> 1) & 1;            // feature half
    const int gid = blockIdx.x * 64 + pl;     // 0..32767
    const int b = gid >> 13;
    const int n = gid & (NPTS - 1);
    const float* cb = cloud + (size_t)b * NPTS * 3;

    // ---- quad-parallel feature build ----
    {
        const float cx = cb[n * 3 + 0];       // same addr across quad (broadcast)
        const float cy = cb[n * 3 + 1];
        const float cz = cb[n * 3 + 2];

        // neighbor ownership: s=0:{0,1,2} s=1:{3,4,5} s=2:{6,7} s=3:{8,9}
        const int kbase = (s == 0) ? 0 : (s == 1) ? 3 : (s == 2) ? 6 : 8;
        const int kcnt  = (s < 2) ? 3 : 2;

        float nx[3], ny[3], nz[3];
        const unsigned short* ki = knn_idx + (size_t)gid * KNN;
        for (int kk = 0; kk < kcnt; ++kk) {
            const int j = ki[kbase + kk];
            nx[kk] = cb[j * 3 + 0];
            ny[kk] = cb[j * 3 + 1];
            nz[kk] = cb[j * 3 + 2];
        }

        float* fr = fs[pl];
        if (s == 0) { fr[0] = cx; fr[1] = cy; fr[2] = cz; }
        for (int kk = 0; kk < kcnt; ++kk) {
            const int k = kbase + kk;
            fr[3 + 3 * k + 0] = nx[kk];
            fr[3 + 3 * k + 1] = ny[kk];
            fr[3 + 3 * k + 2] = nz[kk];
            const float rx = nx[kk] - cx, ry = ny[kk] - cy, rz = nz[kk] - cz;
            fr[33 + 3 * k + 0] = rx;
            fr[33 + 3 * k + 1] = ry;
            fr[33 + 3 * k + 2] = rz;
            fr[63 + k] = sqrtf(fmaf(rz, rz, fmaf(ry, ry, rx * rx)));
        }

        // quad-reduced mean
        float smx = 0.f, smy = 0.f, smz = 0.f;
        for (int kk = 0; kk < kcnt; ++kk) { smx += nx[kk]; smy += ny[kk]; smz += nz[kk]; }
#define QSUM(v) { v += __shfl_xor(v, 1, 64); v += __shfl_xor(v, 2, 64); }
        QSUM(smx); QSUM(smy); QSUM(smz);
        const float mx = smx * (1.0f / KNN);
        const float my = smy * (1.0f / KNN);
        const float mz = smz * (1.0f / KNN);

        // quad-reduced covariance partials
        float c00 = 0.f, c01 = 0.f, c02 = 0.f, c11 = 0.f, c12 = 0.f, c22 = 0.f;
        for (int kk = 0; kk < kcnt; ++kk) {
            const float ex = nx[kk] - mx, ey = ny[kk] - my, ez = nz[kk] - mz;
            c00 = fmaf(ex, ex, c00); c01 = fmaf(ex, ey, c01); c02 = fmaf(ex, ez, c02);
            c11 = fmaf(ey, ey, c11); c12 = fmaf(ey, ez, c12); c22 = fmaf(ez, ez, c22);
        }
        QSUM(c00); QSUM(c01); QSUM(c02); QSUM(c11); QSUM(c12); QSUM(c22);
#undef QSUM
        const float sc = 1.0f / (KNN - 1);
        c00 *= sc; c01 *= sc; c02 *= sc; c11 *= sc; c12 *= sc; c22 *= sc;

        // fp32 closed-form symmetric 3x3 eigenvalues (all 4 lanes, same time)
        const float qd = (c00 + c11 + c22) * (1.0f / 3.0f);
        const float pp1 = c01 * c01 + c02 * c02 + c12 * c12;
        const float d00 = c00 - qd, d11 = c11 - qd, d22 = c22 - qd;
        const float p2 = d00 * d00 + d11 * d11 + d22 * d22 + 2.0f * pp1;
        float l1, l2, l3;
        if (p2 < 1e-30f) {
            l1 = l2 = l3 = qd;
        } else {
            const float p = sqrtf(p2 * (1.0f / 6.0f));
            const float inv = 1.0f / p;
            const float e00 = d00 * inv, e11 = d11 * inv, e22 = d22 * inv;
            const float e01 = c01 * inv, e02 = c02 * inv, e12 = c12 * inv;
            float detB = e00 * (e11 * e22 - e12 * e12)
                       - e01 * (e01 * e22 - e12 * e02)
                       + e02 * (e01 * e12 - e11 * e02);
            float r = 0.5f * detB;
            r = fminf(1.0f, fmaxf(-1.0f, r));
            const float phi = acosf(r) * (1.0f / 3.0f);
            l1 = qd + 2.0f * p * __cosf(phi);                          // largest
            l3 = qd + 2.0f * p * __cosf(phi + 2.0943951023931953f);    // smallest
            l2 = 3.0f * qd - l1 - l3;
        }
        if (s == 0) {
            fr[73] = (l1 - l2) / l1;
            fr[74] = (l2 - l3) / l1;
            fr[75] = l3 / l1;
        }
    }

    __syncthreads();   // weights + features visible

    const float* fr = fs[pl];
    const int f0 = subf * 38;

    float h[32];
#pragma unroll
    for (int j = 0; j < 32; ++j) h[j] = (subf == 0) ? b1s[subh * 32 + j] : 0.0f;

#pragma unroll 2
    for (int ff = 0; ff < 38; ++ff) {
        const int f = f0 + ff;
        const float v = fr[f];
        const float4* w4 = reinterpret_cast<const float4*>(w1s + f * 68 + subh * 32);
#pragma unroll
        for (int j4 = 0; j4 < 8; ++j4) {
            const float4 w = w4[j4];
            h[4 * j4 + 0] = fmaf(v, w.x, h[4 * j4 + 0]);
            h[4 * j4 + 1] = fmaf(v, w.y, h[4 * j4 + 1]);
            h[4 * j4 + 2] = fmaf(v, w.z, h[4 * j4 + 2]);
            h[4 * j4 + 3] = fmaf(v, w.w, h[4 * j4 + 3]);
        }
    }

    // combine feature halves (lanes differing in bit 1)
#pragma unroll
    for (int j = 0; j < 32; ++j) h[j] += __shfl_xor(h[j], 2, 64);

    float o0 = 0.f, o1 = 0.f, o2 = 0.f;
#pragma unroll
    for (int j = 0; j < 32; ++j) {
        const float r = fmaxf(h[j], 0.0f);
        const int jj = subh * 32 + j;
        o0 = fmaf(r, w2s[jj * 3 + 0], o0);
        o1 = fmaf(r, w2s[jj * 3 + 1], o1);
        o2 = fmaf(r, w2s[jj * 3 + 2], o2);
    }
    // combine hidden halves (lanes differing in bit 0)
    o0 += __shfl_xor(o0, 1, 64);
    o1 += __shfl_xor(o1, 1, 64);
    o2 += __shfl_xor(o2, 1, 64);

    if ((t & 3) == 0) {
        float* op = out + (size_t)gid * 3;
        op[0] = fmaxf(o0 + b2s[0], 0.0f);
        op[1] = fmaxf(o1 + b2s[1], 0.0f);
        op[2] = fmaxf(o2 + b2s[2], 0.0f);
    }
}

extern "C" void kernel_launch(void* const* d_in, const int* in_sizes, int n_in,
                              void* d_out, int out_size, void* d_ws, size_t ws_size,
                              hipStream_t stream) {
    const float* cloud = (const float*)d_in[0];   // [4,8192,3]
    const float* W1    = (const float*)d_in[1];   // [76,64]
    const float* b1    = (const float*)d_in[2];   // [64]
    const float* W2    = (const float*)d_in[3];   // [64,3]
    const float* b2    = (const float*)d_in[4];   // [3]
    float* out = (float*)d_out;                   // [4,8192,3]

    unsigned short* knn = (unsigned short*)d_ws;  // 640 KB

    knn_kernel<<<dim3(1024), dim3(512), 0, stream>>>(cloud, knn);
    feat_mlp_kernel<<<dim3(512), dim3(256), 0, stream>>>(cloud, W1, b1, W2, b2, knn, out);
}

// Round 2
// 167.915 us; speedup vs baseline: 1.0275x; 1.0233x over previous
//
#include <hip/hip_runtime.h>
#include <math.h>

#define KNN    10
#define NPTS   8192
#define HID    64
#define NF     76
#define Q      16                // queries per wave
#define CAP    64                // pass-2 collection capacity per query
#define F32_INF __uint_as_float(0x7F800000u)

__device__ __forceinline__ float rl(float v, int lane) {
    return __int_as_float(__builtin_amdgcn_readlane(__float_as_int(v), lane));
}

// ---------------------------------------------------------------------------
// KNN — R18 structure, R21 change: SGPR-resident query coordinates.
//   Evidence (R19/R20): VGPR_Count=52 with or without (512,4) bound, but the
//   hot loop's vector live set would be 70+ if qxs/qys/qzs[16]+vmin[16] were
//   VGPR-resident -> compiler is spilling/rematerializing the query arrays
//   every tile (3x VALU inflation: 87us issue vs 29us model; FETCH stays low
//   because scratch reloads hit L1/L2). Root cause: qxs[qq] is wave-uniform
//   (same address all lanes) but uniformity analysis can't prove it (indices
//   derive from threadIdx), so no scalarization.
//   Fix: lanes 0-15 load the 16 queries' coords; 48 readlanes (once, before
//   the tile loops) produce provably-uniform values -> SGPRs. Inner loop is
//   exactly 3 v_fma (1 SGPR operand each, legal) + 1 v_min per query; vector
//   live set ~30 VGPRs. Bit-identical values (readlane moves exact bits).
// Selection chain untouched (validated 10+ rounds): inline w, transposed
// scan, rank-11 chunk-minima threshold + 1e-3, exact R1-chain key rebuild,
// top-11 + filter.
// ---------------------------------------------------------------------------
__global__ __launch_bounds__(512) void knn_kernel(const float* __restrict__ cloud,
                                                  unsigned short* __restrict__ knn_idx) {
    __shared__ unsigned long long coll[CAP][33];   // 16.9 KB
    __shared__ float pk[8][Q][17];                 // 8.7 KB
    __shared__ float tau_s[32];
    __shared__ int   cnt[32];

    const int t    = threadIdx.x;
    const int w    = t >> 6;                  // wave 0..7
    const int lane = t & 63;
    const int g    = w >> 2;                  // query group 0..1
    const int h    = w & 3;                   // candidate quarter 0..3
    const int bx   = blockIdx.x;              // 0..1023
    const int b    = bx >> 8;                 // batch
    const int n_base = (bx & 255) * 32 + g * Q;   // batch-local first query of group
    const int lq_base = g * Q;                // block-local query base
    const int cb0 = h * (NPTS / 4);           // candidate base for this wave

    const float* cb = cloud + (size_t)b * NPTS * 3;

    if (t < 32) cnt[t] = 0;                   // visible after barrier 1

    // ---- query coords -> SGPRs via readlane (R21) ----
    // lane qq (0..15, replicated x4) loads query qq's x,y,z; readlane makes
    // them wave-uniform so the allocator puts them in SGPRs, not VGPRs.
    float qx_s[Q], qy_s[Q], qz_s[Q];
    {
        const int ql = n_base + (lane & 15);
        const float lx = cb[ql * 3 + 0];
        const float ly = cb[ql * 3 + 1];
        const float lz = cb[ql * 3 + 2];
#pragma unroll
        for (int qq = 0; qq < Q; ++qq) {
            qx_s[qq] = rl(lx, qq);
            qy_s[qq] = rl(ly, qq);
            qz_s[qq] = rl(lz, qq);
        }
    }

    // ---------------- pass 1: per-lane minima over this quarter ----------------
    float vmin[Q];
#pragma unroll
    for (int qq = 0; qq < Q; ++qq) vmin[qq] = F32_INF;

    float cx0 = cb[(cb0 + lane) * 3 + 0];
    float cy0 = cb[(cb0 + lane) * 3 + 1];
    float cz0 = cb[(cb0 + lane) * 3 + 2];
    for (int ti = 0; ti < NPTS / 4 / 64; ++ti) {  // 32 tiles
        float nx0 = cx0, ny0 = cy0, nz0 = cz0;
        if (ti < NPTS / 4 / 64 - 1) {
            const int c1 = cb0 + (ti + 1) * 64 + lane;
            nx0 = cb[c1 * 3 + 0]; ny0 = cb[c1 * 3 + 1]; nz0 = cb[c1 * 3 + 2];
        }
        const float aw  = fmaf(cz0, cz0, fmaf(cy0, cy0, cx0 * cx0));  // prep expr
        const float a2x = -2.0f * cx0;
        const float a2y = -2.0f * cy0;
        const float a2z = -2.0f * cz0;
#pragma unroll
        for (int qq = 0; qq < Q; ++qq) {
            const float v = fmaf(a2x, qx_s[qq], fmaf(a2y, qy_s[qq], fmaf(a2z, qz_s[qq], aw)));
            vmin[qq] = fminf(vmin[qq], v);    // self included (rank arg handles it)
        }
        cx0 = nx0; cy0 = ny0; cz0 = nz0;
    }

#pragma unroll
    for (int qq = 0; qq < Q; ++qq) {
        float v = vmin[qq];
        v = fminf(v, __shfl_xor(v, 32, 64));
        v = fminf(v, __shfl_xor(v, 16, 64));
        if (lane < 16) pk[w][qq][lane] = v;
    }
    __syncthreads();                          // barrier 1: pk + cnt visible

    // h==0 waves: 11th smallest of 64 chunk minima -> tau for group
    if (h == 0) {
        float md[KNN + 1];
#pragma unroll
        for (int s = 0; s <= KNN; ++s) md[s] = F32_INF;
        const int qsel = lane & 15;           // 4-way replicated
#pragma unroll
        for (int cc = 0; cc < 64; ++cc) {
            float d = pk[g * 4 + (cc >> 4)][qsel][cc & 15];
#pragma unroll
            for (int u = 0; u <= KNN; ++u) {
                const float lo = fminf(md[u], d);
                d = fmaxf(md[u], d);
                md[u] = lo;
            }
        }
        if (lane < 16) tau_s[lq_base + lane] = md[KNN] + 1e-3f;
    }
    __syncthreads();                          // barrier 2: tau visible

    float taum[Q];
    {
        const float tv = tau_s[lq_base + (lane & 15)];
#pragma unroll
        for (int qq = 0; qq < Q; ++qq) taum[qq] = rl(tv, qq);   // -> SGPRs
    }

    // ---------------- pass 2: collect hits incl. self (rare) ----------------
    float cx2 = cb[(cb0 + lane) * 3 + 0];
    float cy2 = cb[(cb0 + lane) * 3 + 1];
    float cz2 = cb[(cb0 + lane) * 3 + 2];
    int jcur = cb0 + lane;
    for (int ti = 0; ti < NPTS / 4 / 64; ++ti) {
        float nx2 = cx2, ny2 = cy2, nz2 = cz2;
        if (ti < NPTS / 4 / 64 - 1) {
            const int c1 = cb0 + (ti + 1) * 64 + lane;
            nx2 = cb[c1 * 3 + 0]; ny2 = cb[c1 * 3 + 1]; nz2 = cb[c1 * 3 + 2];
        }
        const float aw  = fmaf(cz2, cz2, fmaf(cy2, cy2, cx2 * cx2));
        const float a2x = -2.0f * cx2;
        const float a2y = -2.0f * cy2;
        const float a2z = -2.0f * cz2;
#pragma unroll
        for (int qq = 0; qq < Q; ++qq) {
            const float v = fmaf(a2x, qx_s[qq], fmaf(a2y, qy_s[qq], fmaf(a2z, qz_s[qq], aw)));
            if (__builtin_expect(v <= taum[qq], 0)) {
                // EXACT key: R1-chain d2 expression (qs recomputed, identical
                // fmaf chain on identical bits).
                const float qs = fmaf(qz_s[qq], qz_s[qq],
                                      fmaf(qy_s[qq], qy_s[qq], qx_s[qq] * qx_s[qq]));
                const float dot = fmaf(cz2, qz_s[qq], fmaf(cy2, qy_s[qq], cx2 * qx_s[qq]));
                const float d2 = fmaf(-2.0f, dot, qs + aw);
                const unsigned int fb = __float_as_uint(d2);
                const unsigned int m =
                    fb ^ ((unsigned int)((int)fb >> 31) | 0x80000000u);  // monotone
                const unsigned long long key =
                    ((unsigned long long)m << 13) | (unsigned long long)(unsigned)jcur;
                const int slot = atomicAdd(&cnt[lq_base + qq], 1);
                if (slot < CAP) coll[slot][lq_base + qq] = key;
            }
        }
        cx2 = nx2; cy2 = ny2; cz2 = nz2;
        jcur += 64;
    }
    __syncthreads();

    // ---------------- phase 3: top-11 bubble, filter self by index ----------
    if (t < 32) {
        const int m = cnt[t];
        int mc = m;
#pragma unroll
        for (int off = 1; off < 32; off <<= 1)        // 32 active lanes only
            mc = max(mc, __shfl_xor(mc, off, 64));
        mc = __builtin_amdgcn_readfirstlane(mc);

        const int n = (bx & 255) * 32 + t;    // this lane's batch-local query

        unsigned long long md[KNN + 1];
#pragma unroll
        for (int s = 0; s <= KNN; ++s) md[s] = ~0ULL;

        if (mc <= CAP) {
            for (int cc = 0; cc < mc; ++cc) {
                unsigned long long key = (cc < m) ? coll[cc][t] : ~0ULL;
#pragma unroll
                for (int u = 0; u <= KNN; ++u) {
                    const bool lt = key < md[u];
                    const unsigned long long lo = lt ? key : md[u];
                    key = lt ? md[u] : key;
                    md[u] = lo;
                }
            }
        } else {
            // exact serial fallback (never expected): full rescan, inline w
            const float qx = cb[n * 3 + 0];
            const float qy = cb[n * 3 + 1];
            const float qz = cb[n * 3 + 2];
            const float qs = fmaf(qz, qz, fmaf(qy, qy, qx * qx));
            for (int j = 0; j < NPTS; ++j) {
                const float px = cb[j * 3 + 0];
                const float py = cb[j * 3 + 1];
                const float pz = cb[j * 3 + 2];
                const float pw = fmaf(pz, pz, fmaf(py, py, px * px));
                const float dot = fmaf(pz, qz, fmaf(py, qy, px * qx));
                const float d2 = fmaf(-2.0f, dot, qs + pw);
                const unsigned int fb = __float_as_uint(d2);
                const unsigned int mm =
                    fb ^ ((unsigned int)((int)fb >> 31) | 0x80000000u);
                unsigned long long key =
                    ((unsigned long long)mm << 13) | (unsigned long long)j;
                key = (j == n) ? ~0ULL : key;
#pragma unroll
                for (int u = 0; u <= KNN; ++u) {
                    const bool lt = key < md[u];
                    const unsigned long long lo = lt ? key : md[u];
                    key = lt ? md[u] : key;
                    md[u] = lo;
                }
            }
        }

        unsigned short* outp = knn_idx + ((size_t)b * NPTS + n) * KNN;
        int outc = 0;
#pragma unroll
        for (int u = 0; u <= KNN; ++u) {
            const int idx = (int)(md[u] & 8191u);
            if (outc < KNN && idx != n) outp[outc++] = (unsigned short)idx;
        }
    }
}

// ---------------------------------------------------------------------------
// Features + MLP — R18 config with QUAD-PARALLEL feature build (R19 change):
// the build previously ran on 1 of 4 lanes (10 serial gathers + cov + eigen
// = the longest unhidden chain at 2 waves/SIMD). Now lanes own 3/3/2/2
// neighbors (gather depth 10->3, same total fr LDS writes, just spread);
// mean/cov via quad partial sums + shfl_xor(1,2) reduces (~18 added shfl ops
// vs ~304 ds_read_b128/thread — negligible DS add, unlike R13's butterfly).
// Eigen redundant on all 4 lanes (same wave time), lane 0 writes.
// Tree-summed mean/cov: R13 used this pattern, absmax bit-identical.
// MLP part unchanged (best-measured R12/R14 layout).
// ---------------------------------------------------------------------------
__global__ __launch_bounds__(256) void feat_mlp_kernel(const float* __restrict__ cloud,
                                                       const float* __restrict__ W1,
                                                       const float* __restrict__ b1,
                                                       const float* __restrict__ W2,
                                                       const float* __restrict__ b2,
                                                       const unsigned short* __restrict__ knn_idx,
                                                       float* __restrict__ out) {
    __shared__ float w1s[NF * 68];            // padded stride
    __shared__ float b1s[HID];
    __shared__ float w2s[HID * 3];
    __shared__ float b2s[3];
    __shared__ float fs[64][NF + 1];          // stride 77

    const int t = threadIdx.x;
    for (int idx = t; idx < NF * HID; idx += 256)
        w1s[(idx >> 6) * 68 + (idx & 63)] = W1[idx];
    if (t < HID) b1s[t] = b1[t];
    if (t < HID * 3) w2s[t] = W2[t];
    if (t < 3) b2s[t] = b2[t];

    const int pl   = t >> 2;                  // point slot 0..63
    const int s    = t & 3;                   // quad sub-lane
    const int subh = t & 1;                   // hidden half
    const int subf = (t >> 1) & 1;            // feature half
    const int gid = blockIdx.x * 64 + pl;     // 0..32767
    const int b = gid >> 13;
    const int n = gid & (NPTS - 1);
    const float* cb = cloud + (size_t)b * NPTS * 3;

    // ---- quad-parallel feature build ----
    {
        const float cx = cb[n * 3 + 0];       // same addr across quad (broadcast)
        const float cy = cb[n * 3 + 1];
        const float cz = cb[n * 3 + 2];

        // neighbor ownership: s=0:{0,1,2} s=1:{3,4,5} s=2:{6,7} s=3:{8,9}
        const int kbase = (s == 0) ? 0 : (s == 1) ? 3 : (s == 2) ? 6 : 8;
        const int kcnt  = (s < 2) ? 3 : 2;

        float nx[3], ny[3], nz[3];
        const unsigned short* ki = knn_idx + (size_t)gid * KNN;
        for (int kk = 0; kk < kcnt; ++kk) {
            const int j = ki[kbase + kk];
            nx[kk] = cb[j * 3 + 0];
            ny[kk] = cb[j * 3 + 1];
            nz[kk] = cb[j * 3 + 2];
        }

        float* fr = fs[pl];
        if (s == 0) { fr[0] = cx; fr[1] = cy; fr[2] = cz; }
        for (int kk = 0; kk < kcnt; ++kk) {
            const int k = kbase + kk;
            fr[3 + 3 * k + 0] = nx[kk];
            fr[3 + 3 * k + 1] = ny[kk];
            fr[3 + 3 * k + 2] = nz[kk];
            const float rx = nx[kk] - cx, ry = ny[kk] - cy, rz = nz[kk] - cz;
            fr[33 + 3 * k + 0] = rx;
            fr[33 + 3 * k + 1] = ry;
            fr[33 + 3 * k + 2] = rz;
            fr[63 + k] = sqrtf(fmaf(rz, rz, fmaf(ry, ry, rx * rx)));
        }

        // quad-reduced mean
        float smx = 0.f, smy = 0.f, smz = 0.f;
        for (int kk = 0; kk < kcnt; ++kk) { smx += nx[kk]; smy += ny[kk]; smz += nz[kk]; }
#define QSUM(v) { v += __shfl_xor(v, 1, 64); v += __shfl_xor(v, 2, 64); }
        QSUM(smx); QSUM(smy); QSUM(smz);
        const float mx = smx * (1.0f / KNN);
        const float my = smy * (1.0f / KNN);
        const float mz = smz * (1.0f / KNN);

        // quad-reduced covariance partials
        float c00 = 0.f, c01 = 0.f, c02 = 0.f, c11 = 0.f, c12 = 0.f, c22 = 0.f;
        for (int kk = 0; kk < kcnt; ++kk) {
            const float ex = nx[kk] - mx, ey = ny[kk] - my, ez = nz[kk] - mz;
            c00 = fmaf(ex, ex, c00); c01 = fmaf(ex, ey, c01); c02 = fmaf(ex, ez, c02);
            c11 = fmaf(ey, ey, c11); c12 = fmaf(ey, ez, c12); c22 = fmaf(ez, ez, c22);
        }
        QSUM(c00); QSUM(c01); QSUM(c02); QSUM(c11); QSUM(c12); QSUM(c22);
#undef QSUM
        const float sc = 1.0f / (KNN - 1);
        c00 *= sc; c01 *= sc; c02 *= sc; c11 *= sc; c12 *= sc; c22 *= sc;

        // fp32 closed-form symmetric 3x3 eigenvalues (all 4 lanes, same time)
        const float qd = (c00 + c11 + c22) * (1.0f / 3.0f);
        const float pp1 = c01 * c01 + c02 * c02 + c12 * c12;
        const float d00 = c00 - qd, d11 = c11 - qd, d22 = c22 - qd;
        const float p2 = d00 * d00 + d11 * d11 + d22 * d22 + 2.0f * pp1;
        float l1, l2, l3;
        if (p2 < 1e-30f) {
            l1 = l2 = l3 = qd;
        } else {
            const float p = sqrtf(p2 * (1.0f / 6.0f));
            const float inv = 1.0f / p;
            const float e00 = d00 * inv, e11 = d11 * inv, e22 = d22 * inv;
            const float e01 = c01 * inv, e02 = c02 * inv, e12 = c12 * inv;
            float detB = e00 * (e11 * e22 - e12 * e12)
                       - e01 * (e01 * e22 - e12 * e02)
                       + e02 * (e01 * e12 - e11 * e02);
            float r = 0.5f * detB;
            r = fminf(1.0f, fmaxf(-1.0f, r));
            const float phi = acosf(r) * (1.0f / 3.0f);
            l1 = qd + 2.0f * p * __cosf(phi);                          // largest
            l3 = qd + 2.0f * p * __cosf(phi + 2.0943951023931953f);    // smallest
            l2 = 3.0f * qd - l1 - l3;
        }
        if (s == 0) {
            fr[73] = (l1 - l2) / l1;
            fr[74] = (l2 - l3) / l1;
            fr[75] = l3 / l1;
        }
    }

    __syncthreads();   // weights + features visible

    const float* fr = fs[pl];
    const int f0 = subf * 38;

    float h[32];
#pragma unroll
    for (int j = 0; j < 32; ++j) h[j] = (subf == 0) ? b1s[subh * 32 + j] : 0.0f;

#pragma unroll 2
    for (int ff = 0; ff < 38; ++ff) {
        const int f = f0 + ff;
        const float v = fr[f];
        const float4* w4 = reinterpret_cast<const float4*>(w1s + f * 68 + subh * 32);
#pragma unroll
        for (int j4 = 0; j4 < 8; ++j4) {
            const float4 w = w4[j4];
            h[4 * j4 + 0] = fmaf(v, w.x, h[4 * j4 + 0]);
            h[4 * j4 + 1] = fmaf(v, w.y, h[4 * j4 + 1]);
            h[4 * j4 + 2] = fmaf(v, w.z, h[4 * j4 + 2]);
            h[4 * j4 + 3] = fmaf(v, w.w, h[4 * j4 + 3]);
        }
    }

    // combine feature halves (lanes differing in bit 1)
#pragma unroll
    for (int j = 0; j < 32; ++j) h[j] += __shfl_xor(h[j], 2, 64);

    float o0 = 0.f, o1 = 0.f, o2 = 0.f;
#pragma unroll
    for (int j = 0; j < 32; ++j) {
        const float r = fmaxf(h[j], 0.0f);
        const int jj = subh * 32 + j;
        o0 = fmaf(r, w2s[jj * 3 + 0], o0);
        o1 = fmaf(r, w2s[jj * 3 + 1], o1);
        o2 = fmaf(r, w2s[jj * 3 + 2], o2);
    }
    // combine hidden halves (lanes differing in bit 0)
    o0 += __shfl_xor(o0, 1, 64);
    o1 += __shfl_xor(o1, 1, 64);
    o2 += __shfl_xor(o2, 1, 64);

    if ((t & 3) == 0) {
        float* op = out + (size_t)gid * 3;
        op[0] = fmaxf(o0 + b2s[0], 0.0f);
        op[1] = fmaxf(o1 + b2s[1], 0.0f);
        op[2] = fmaxf(o2 + b2s[2], 0.0f);
    }
}

extern "C" void kernel_launch(void* const* d_in, const int* in_sizes, int n_in,
                              void* d_out, int out_size, void* d_ws, size_t ws_size,
                              hipStream_t stream) {
    const float* cloud = (const float*)d_in[0];   // [4,8192,3]
    const float* W1    = (const float*)d_in[1];   // [76,64]
    const float* b1    = (const float*)d_in[2];   // [64]
    const float* W2    = (const float*)d_in[3];   // [64,3]
    const float* b2    = (const float*)d_in[4];   // [3]
    float* out = (float*)d_out;                   // [4,8192,3]

    unsigned short* knn = (unsigned short*)d_ws;  // 640 KB

    knn_kernel<<<dim3(1024), dim3(512), 0, stream>>>(cloud, knn);
    feat_mlp_kernel<<<dim3(512), dim3(256), 0, stream>>>(cloud, W1, b1, W2, b2, knn, out);
}

// Round 3
// 167.383 us; speedup vs baseline: 1.0308x; 1.0032x over previous
//
#include <hip/hip_runtime.h>
#include <math.h>

#define KNN    10
#define NPTS   8192
#define HID    64
#define NF     76
#define Q      16                // queries per wave
#define CAP    64                // pass-2 collection capacity per query
#define F32_INF __uint_as_float(0x7F800000u)

typedef float v2f __attribute__((ext_vector_type(2)));

__device__ __forceinline__ float rl(float v, int lane) {
    return __int_as_float(__builtin_amdgcn_readlane(__float_as_int(v), lane));
}

// ---------------------------------------------------------------------------
// KNN — R18 structure, R21 SGPR-resident queries, R22 change: packed-FP32
// inner loops.
//   Evidence (R21): VALUBusy ~81% at VGPR=28/SGPR=96 -> VALU-issue saturated;
//   occupancy/register fixes can't help further. The dominant instruction
//   class is 4 scalar VALU per (query,candidate) pair x 2 passes.
//   Fix: pack query PAIRS into float2 ext-vectors (wave-uniform -> SGPR
//   pairs; one constant-bus read per op). Inner loop: 3 v_pk_fma_f32 +
//   2 v_min per 2 queries => per-tile issue ~64 -> ~40 (-35% on the
//   saturated pipe). Candidate-side terms duplicated into both halves once
//   per tile (amortized over 16 queries). Also: branchless wrap-around
//   prefetch ((ti+1)&31) kills the per-tile guard.
//   Numerics bit-identical: pk_fma = IEEE fma per half, same chain per
//   query; same candidate->lane->chunk mapping; same tau rank; same exact
//   R1-chain key rebuild. absmax must remain 0.004394531.
// Selection chain untouched (validated 10+ rounds).
// ---------------------------------------------------------------------------
__global__ __launch_bounds__(512) void knn_kernel(const float* __restrict__ cloud,
                                                  unsigned short* __restrict__ knn_idx) {
    __shared__ unsigned long long coll[CAP][33];   // 16.9 KB
    __shared__ float pk[8][Q][17];                 // 8.7 KB
    __shared__ float tau_s[32];
    __shared__ int   cnt[32];

    const int t    = threadIdx.x;
    const int w    = t >> 6;                  // wave 0..7
    const int lane = t & 63;
    const int g    = w >> 2;                  // query group 0..1
    const int h    = w & 3;                   // candidate quarter 0..3
    const int bx   = blockIdx.x;              // 0..1023
    const int b    = bx >> 8;                 // batch
    const int n_base = (bx & 255) * 32 + g * Q;   // batch-local first query of group
    const int lq_base = g * Q;                // block-local query base
    const int cb0 = h * (NPTS / 4);           // candidate base for this wave

    const float* cb = cloud + (size_t)b * NPTS * 3;

    if (t < 32) cnt[t] = 0;                   // visible after barrier 1

    // ---- query coords -> SGPR pairs via readlane (R21/R22) ----
    // lane qq (0..15, replicated x4) loads query qq's x,y,z; readlane makes
    // them wave-uniform; packed as float2 so each v_pk_fma reads one SGPR
    // pair (one constant-bus slot).
    v2f qx_p[8], qy_p[8], qz_p[8];
    {
        const int ql = n_base + (lane & 15);
        const float lx = cb[ql * 3 + 0];
        const float ly = cb[ql * 3 + 1];
        const float lz = cb[ql * 3 + 2];
#pragma unroll
        for (int j = 0; j < 8; ++j) {
            qx_p[j] = (v2f){ rl(lx, 2 * j), rl(lx, 2 * j + 1) };
            qy_p[j] = (v2f){ rl(ly, 2 * j), rl(ly, 2 * j + 1) };
            qz_p[j] = (v2f){ rl(lz, 2 * j), rl(lz, 2 * j + 1) };
        }
    }

    // ---------------- pass 1: per-lane minima over this quarter ----------------
    v2f vmin2[8];
#pragma unroll
    for (int j = 0; j < 8; ++j) vmin2[j] = (v2f){ F32_INF, F32_INF };

    float cx0 = cb[(cb0 + lane) * 3 + 0];
    float cy0 = cb[(cb0 + lane) * 3 + 1];
    float cz0 = cb[(cb0 + lane) * 3 + 2];
    for (int ti = 0; ti < NPTS / 4 / 64; ++ti) {  // 32 tiles
        // branchless wrap-around prefetch (last iter reloads tile 0, dead)
        const int c1 = cb0 + (((ti + 1) & 31) * 64) + lane;
        const float nx0 = cb[c1 * 3 + 0];
        const float ny0 = cb[c1 * 3 + 1];
        const float nz0 = cb[c1 * 3 + 2];
        const float aw  = fmaf(cz0, cz0, fmaf(cy0, cy0, cx0 * cx0));  // prep expr
        const v2f aw2  = (v2f){ aw, aw };
        const v2f a2x2 = (v2f){ -2.0f * cx0, -2.0f * cx0 };
        const v2f a2y2 = (v2f){ -2.0f * cy0, -2.0f * cy0 };
        const v2f a2z2 = (v2f){ -2.0f * cz0, -2.0f * cz0 };
#pragma unroll
        for (int j = 0; j < 8; ++j) {
            const v2f v = __builtin_elementwise_fma(a2x2, qx_p[j],
                          __builtin_elementwise_fma(a2y2, qy_p[j],
                          __builtin_elementwise_fma(a2z2, qz_p[j], aw2)));
            vmin2[j] = __builtin_elementwise_min(vmin2[j], v);  // self included
        }
        cx0 = nx0; cy0 = ny0; cz0 = nz0;
    }

#pragma unroll
    for (int qq = 0; qq < Q; ++qq) {
        float v = vmin2[qq >> 1][qq & 1];
        v = fminf(v, __shfl_xor(v, 32, 64));
        v = fminf(v, __shfl_xor(v, 16, 64));
        if (lane < 16) pk[w][qq][lane] = v;
    }
    __syncthreads();                          // barrier 1: pk + cnt visible

    // h==0 waves: 11th smallest of 64 chunk minima -> tau for group
    if (h == 0) {
        float md[KNN + 1];
#pragma unroll
        for (int s = 0; s <= KNN; ++s) md[s] = F32_INF;
        const int qsel = lane & 15;           // 4-way replicated
#pragma unroll
        for (int cc = 0; cc < 64; ++cc) {
            float d = pk[g * 4 + (cc >> 4)][qsel][cc & 15];
#pragma unroll
            for (int u = 0; u <= KNN; ++u) {
                const float lo = fminf(md[u], d);
                d = fmaxf(md[u], d);
                md[u] = lo;
            }
        }
        if (lane < 16) tau_s[lq_base + lane] = md[KNN] + 1e-3f;
    }
    __syncthreads();                          // barrier 2: tau visible

    float taum[Q];
    {
        const float tv = tau_s[lq_base + (lane & 15)];
#pragma unroll
        for (int qq = 0; qq < Q; ++qq) taum[qq] = rl(tv, qq);   // -> SGPRs
    }

    // ---------------- pass 2: collect hits incl. self (rare) ----------------
    float cx2 = cb[(cb0 + lane) * 3 + 0];
    float cy2 = cb[(cb0 + lane) * 3 + 1];
    float cz2 = cb[(cb0 + lane) * 3 + 2];
    int jcur = cb0 + lane;
    for (int ti = 0; ti < NPTS / 4 / 64; ++ti) {
        const int c1 = cb0 + (((ti + 1) & 31) * 64) + lane;
        const float nx2 = cb[c1 * 3 + 0];
        const float ny2 = cb[c1 * 3 + 1];
        const float nz2 = cb[c1 * 3 + 2];
        const float aw  = fmaf(cz2, cz2, fmaf(cy2, cy2, cx2 * cx2));
        const v2f aw2  = (v2f){ aw, aw };
        const v2f a2x2 = (v2f){ -2.0f * cx2, -2.0f * cx2 };
        const v2f a2y2 = (v2f){ -2.0f * cy2, -2.0f * cy2 };
        const v2f a2z2 = (v2f){ -2.0f * cz2, -2.0f * cz2 };
#pragma unroll
        for (int j = 0; j < 8; ++j) {
            const v2f v = __builtin_elementwise_fma(a2x2, qx_p[j],
                          __builtin_elementwise_fma(a2y2, qy_p[j],
                          __builtin_elementwise_fma(a2z2, qz_p[j], aw2)));
#pragma unroll
            for (int half = 0; half < 2; ++half) {
                const int qq = 2 * j + half;
                if (__builtin_expect(v[half] <= taum[qq], 0)) {
                    // EXACT key: R1-chain d2 expression on identical bits.
                    const float qx = qx_p[j][half];
                    const float qy = qy_p[j][half];
                    const float qz = qz_p[j][half];
                    const float qs = fmaf(qz, qz, fmaf(qy, qy, qx * qx));
                    const float dot = fmaf(cz2, qz, fmaf(cy2, qy, cx2 * qx));
                    const float d2 = fmaf(-2.0f, dot, qs + aw);
                    const unsigned int fb = __float_as_uint(d2);
                    const unsigned int m =
                        fb ^ ((unsigned int)((int)fb >> 31) | 0x80000000u);  // monotone
                    const unsigned long long key =
                        ((unsigned long long)m << 13) | (unsigned long long)(unsigned)jcur;
                    const int slot = atomicAdd(&cnt[lq_base + qq], 1);
                    if (slot < CAP) coll[slot][lq_base + qq] = key;
                }
            }
        }
        cx2 = nx2; cy2 = ny2; cz2 = nz2;
        jcur += 64;
    }
    __syncthreads();

    // ---------------- phase 3: top-11 bubble, filter self by index ----------
    if (t < 32) {
        const int m = cnt[t];
        int mc = m;
#pragma unroll
        for (int off = 1; off < 32; off <<= 1)        // 32 active lanes only
            mc = max(mc, __shfl_xor(mc, off, 64));
        mc = __builtin_amdgcn_readfirstlane(mc);

        const int n = (bx & 255) * 32 + t;    // this lane's batch-local query

        unsigned long long md[KNN + 1];
#pragma unroll
        for (int s = 0; s <= KNN; ++s) md[s] = ~0ULL;

        if (mc <= CAP) {
            for (int cc = 0; cc < mc; ++cc) {
                unsigned long long key = (cc < m) ? coll[cc][t] : ~0ULL;
#pragma unroll
                for (int u = 0; u <= KNN; ++u) {
                    const bool lt = key < md[u];
                    const unsigned long long lo = lt ? key : md[u];
                    key = lt ? md[u] : key;
                    md[u] = lo;
                }
            }
        } else {
            // exact serial fallback (never expected): full rescan, inline w
            const float qx = cb[n * 3 + 0];
            const float qy = cb[n * 3 + 1];
            const float qz = cb[n * 3 + 2];
            const float qs = fmaf(qz, qz, fmaf(qy, qy, qx * qx));
            for (int j = 0; j < NPTS; ++j) {
                const float px = cb[j * 3 + 0];
                const float py = cb[j * 3 + 1];
                const float pz = cb[j * 3 + 2];
                const float pw = fmaf(pz, pz, fmaf(py, py, px * px));
                const float dot = fmaf(pz, qz, fmaf(py, qy, px * qx));
                const float d2 = fmaf(-2.0f, dot, qs + pw);
                const unsigned int fb = __float_as_uint(d2);
                const unsigned int mm =
                    fb ^ ((unsigned int)((int)fb >> 31) | 0x80000000u);
                unsigned long long key =
                    ((unsigned long long)mm << 13) | (unsigned long long)j;
                key = (j == n) ? ~0ULL : key;
#pragma unroll
                for (int u = 0; u <= KNN; ++u) {
                    const bool lt = key < md[u];
                    const unsigned long long lo = lt ? key : md[u];
                    key = lt ? md[u] : key;
                    md[u] = lo;
                }
            }
        }

        unsigned short* outp = knn_idx + ((size_t)b * NPTS + n) * KNN;
        int outc = 0;
#pragma unroll
        for (int u = 0; u <= KNN; ++u) {
            const int idx = (int)(md[u] & 8191u);
            if (outc < KNN && idx != n) outp[outc++] = (unsigned short)idx;
        }
    }
}

// ---------------------------------------------------------------------------
// Features + MLP — R18 config with QUAD-PARALLEL feature build (R19 change):
// the build previously ran on 1 of 4 lanes (10 serial gathers + cov + eigen
// = the longest unhidden chain at 2 waves/SIMD). Now lanes own 3/3/2/2
// neighbors (gather depth 10->3, same total fr LDS writes, just spread);
// mean/cov via quad partial sums + shfl_xor(1,2) reduces (~18 added shfl ops
// vs ~304 ds_read_b128/thread — negligible DS add, unlike R13's butterfly).
// Eigen redundant on all 4 lanes (same wave time), lane 0 writes.
// Tree-summed mean/cov: R13 used this pattern, absmax bit-identical.
// MLP part unchanged (best-measured R12/R14 layout).
// ---------------------------------------------------------------------------
__global__ __launch_bounds__(256) void feat_mlp_kernel(const float* __restrict__ cloud,
                                                       const float* __restrict__ W1,
                                                       const float* __restrict__ b1,
                                                       const float* __restrict__ W2,
                                                       const float* __restrict__ b2,
                                                       const unsigned short* __restrict__ knn_idx,
                                                       float* __restrict__ out) {
    __shared__ float w1s[NF * 68];            // padded stride
    __shared__ float b1s[HID];
    __shared__ float w2s[HID * 3];
    __shared__ float b2s[3];
    __shared__ float fs[64][NF + 1];          // stride 77

    const int t = threadIdx.x;
    for (int idx = t; idx < NF * HID; idx += 256)
        w1s[(idx >> 6) * 68 + (idx & 63)] = W1[idx];
    if (t < HID) b1s[t] = b1[t];
    if (t < HID * 3) w2s[t] = W2[t];
    if (t < 3) b2s[t] = b2[t];

    const int pl   = t >> 2;                  // point slot 0..63
    const int s    = t & 3;                   // quad sub-lane
    const int subh = t & 1;                   // hidden half
    const int subf = (t >> 1) & 1;            // feature half
    const int gid = blockIdx.x * 64 + pl;     // 0..32767
    const int b = gid >> 13;
    const int n = gid & (NPTS - 1);
    const float* cb = cloud + (size_t)b * NPTS * 3;

    // ---- quad-parallel feature build ----
    {
        const float cx = cb[n * 3 + 0];       // same addr across quad (broadcast)
        const float cy = cb[n * 3 + 1];
        const float cz = cb[n * 3 + 2];

        // neighbor ownership: s=0:{0,1,2} s=1:{3,4,5} s=2:{6,7} s=3:{8,9}
        const int kbase = (s == 0) ? 0 : (s == 1) ? 3 : (s == 2) ? 6 : 8;
        const int kcnt  = (s < 2) ? 3 : 2;

        float nx[3], ny[3], nz[3];
        const unsigned short* ki = knn_idx + (size_t)gid * KNN;
        for (int kk = 0; kk < kcnt; ++kk) {
            const int j = ki[kbase + kk];
            nx[kk] = cb[j * 3 + 0];
            ny[kk] = cb[j * 3 + 1];
            nz[kk] = cb[j * 3 + 2];
        }

        float* fr = fs[pl];
        if (s == 0) { fr[0] = cx; fr[1] = cy; fr[2] = cz; }
        for (int kk = 0; kk < kcnt; ++kk) {
            const int k = kbase + kk;
            fr[3 + 3 * k + 0] = nx[kk];
            fr[3 + 3 * k + 1] = ny[kk];
            fr[3 + 3 * k + 2] = nz[kk];
            const float rx = nx[kk] - cx, ry = ny[kk] - cy, rz = nz[kk] - cz;
            fr[33 + 3 * k + 0] = rx;
            fr[33 + 3 * k + 1] = ry;
            fr[33 + 3 * k + 2] = rz;
            fr[63 + k] = sqrtf(fmaf(rz, rz, fmaf(ry, ry, rx * rx)));
        }

        // quad-reduced mean
        float smx = 0.f, smy = 0.f, smz = 0.f;
        for (int kk = 0; kk < kcnt; ++kk) { smx += nx[kk]; smy += ny[kk]; smz += nz[kk]; }
#define QSUM(v) { v += __shfl_xor(v, 1, 64); v += __shfl_xor(v, 2, 64); }
        QSUM(smx); QSUM(smy); QSUM(smz);
        const float mx = smx * (1.0f / KNN);
        const float my = smy * (1.0f / KNN);
        const float mz = smz * (1.0f / KNN);

        // quad-reduced covariance partials
        float c00 = 0.f, c01 = 0.f, c02 = 0.f, c11 = 0.f, c12 = 0.f, c22 = 0.f;
        for (int kk = 0; kk < kcnt; ++kk) {
            const float ex = nx[kk] - mx, ey = ny[kk] - my, ez = nz[kk] - mz;
            c00 = fmaf(ex, ex, c00); c01 = fmaf(ex, ey, c01); c02 = fmaf(ex, ez, c02);
            c11 = fmaf(ey, ey, c11); c12 = fmaf(ey, ez, c12); c22 = fmaf(ez, ez, c22);
        }
        QSUM(c00); QSUM(c01); QSUM(c02); QSUM(c11); QSUM(c12); QSUM(c22);
#undef QSUM
        const float sc = 1.0f / (KNN - 1);
        c00 *= sc; c01 *= sc; c02 *= sc; c11 *= sc; c12 *= sc; c22 *= sc;

        // fp32 closed-form symmetric 3x3 eigenvalues (all 4 lanes, same time)
        const float qd = (c00 + c11 + c22) * (1.0f / 3.0f);
        const float pp1 = c01 * c01 + c02 * c02 + c12 * c12;
        const float d00 = c00 - qd, d11 = c11 - qd, d22 = c22 - qd;
        const float p2 = d00 * d00 + d11 * d11 + d22 * d22 + 2.0f * pp1;
        float l1, l2, l3;
        if (p2 < 1e-30f) {
            l1 = l2 = l3 = qd;
        } else {
            const float p = sqrtf(p2 * (1.0f / 6.0f));
            const float inv = 1.0f / p;
            const float e00 = d00 * inv, e11 = d11 * inv, e22 = d22 * inv;
            const float e01 = c01 * inv, e02 = c02 * inv, e12 = c12 * inv;
            float detB = e00 * (e11 * e22 - e12 * e12)
                       - e01 * (e01 * e22 - e12 * e02)
                       + e02 * (e01 * e12 - e11 * e02);
            float r = 0.5f * detB;
            r = fminf(1.0f, fmaxf(-1.0f, r));
            const float phi = acosf(r) * (1.0f / 3.0f);
            l1 = qd + 2.0f * p * __cosf(phi);                          // largest
            l3 = qd + 2.0f * p * __cosf(phi + 2.0943951023931953f);    // smallest
            l2 = 3.0f * qd - l1 - l3;
        }
        if (s == 0) {
            fr[73] = (l1 - l2) / l1;
            fr[74] = (l2 - l3) / l1;
            fr[75] = l3 / l1;
        }
    }

    __syncthreads();   // weights + features visible

    const float* fr = fs[pl];
    const int f0 = subf * 38;

    float h[32];
#pragma unroll
    for (int j = 0; j < 32; ++j) h[j] = (subf == 0) ? b1s[subh * 32 + j] : 0.0f;

#pragma unroll 2
    for (int ff = 0; ff < 38; ++ff) {
        const int f = f0 + ff;
        const float v = fr[f];
        const float4* w4 = reinterpret_cast<const float4*>(w1s + f * 68 + subh * 32);
#pragma unroll
        for (int j4 = 0; j4 < 8; ++j4) {
            const float4 w = w4[j4];
            h[4 * j4 + 0] = fmaf(v, w.x, h[4 * j4 + 0]);
            h[4 * j4 + 1] = fmaf(v, w.y, h[4 * j4 + 1]);
            h[4 * j4 + 2] = fmaf(v, w.z, h[4 * j4 + 2]);
            h[4 * j4 + 3] = fmaf(v, w.w, h[4 * j4 + 3]);
        }
    }

    // combine feature halves (lanes differing in bit 1)
#pragma unroll
    for (int j = 0; j < 32; ++j) h[j] += __shfl_xor(h[j], 2, 64);

    float o0 = 0.f, o1 = 0.f, o2 = 0.f;
#pragma unroll
    for (int j = 0; j < 32; ++j) {
        const float r = fmaxf(h[j], 0.0f);
        const int jj = subh * 32 + j;
        o0 = fmaf(r, w2s[jj * 3 + 0], o0);
        o1 = fmaf(r, w2s[jj * 3 + 1], o1);
        o2 = fmaf(r, w2s[jj * 3 + 2], o2);
    }
    // combine hidden halves (lanes differing in bit 0)
    o0 += __shfl_xor(o0, 1, 64);
    o1 += __shfl_xor(o1, 1, 64);
    o2 += __shfl_xor(o2, 1, 64);

    if ((t & 3) == 0) {
        float* op = out + (size_t)gid * 3;
        op[0] = fmaxf(o0 + b2s[0], 0.0f);
        op[1] = fmaxf(o1 + b2s[1], 0.0f);
        op[2] = fmaxf(o2 + b2s[2], 0.0f);
    }
}

extern "C" void kernel_launch(void* const* d_in, const int* in_sizes, int n_in,
                              void* d_out, int out_size, void* d_ws, size_t ws_size,
                              hipStream_t stream) {
    const float* cloud = (const float*)d_in[0];   // [4,8192,3]
    const float* W1    = (const float*)d_in[1];   // [76,64]
    const float* b1    = (const float*)d_in[2];   // [64]
    const float* W2    = (const float*)d_in[3];   // [64,3]
    const float* b2    = (const float*)d_in[4];   // [3]
    float* out = (float*)d_out;                   // [4,8192,3]

    unsigned short* knn = (unsigned short*)d_ws;  // 640 KB

    knn_kernel<<<dim3(1024), dim3(512), 0, stream>>>(cloud, knn);
    feat_mlp_kernel<<<dim3(512), dim3(256), 0, stream>>>(cloud, W1, b1, W2, b2, knn, out);
}